// Round 8
// baseline (34.500 us; speedup 1.0000x reference)
//
#include <hip/hip_runtime.h>
#include <hip/hip_bf16.h>

#define M_DIM 4096
#define N_DIM 8192
#define D_DIM 256
#define NSLICE 32                    /* 256-col slices of N */
#define NCHUNK 16                    /* 16-col chunks per slice */
#define LOOKAHEAD 4
#define C_EXP (-0.7213475204444817f) /* -1/(2 ln2): exp(-d/2) = 2^(d*C_EXP) */
#define K_ACC (1.4426950408889634f)  /* -2*C_EXP: acc coefficient */
#define SKIP_THR (-151.0f)           /* exp2f(x)==0.0f exactly for x<=-151 */
#define BUFB 8192                    /* one 16-col B chunk: 16 x 512 B */
#define SQAL_OFF (8 * BUFB)          /* sqal slice: 256 x 8 B = 2 KB */
#define LDS_BYTES (8 * BUFB + 2048)  /* 66 KiB -> 2 blocks/CU */

typedef __attribute__((ext_vector_type(8))) short short8; // 8 bf16 = 4 VGPR
typedef __attribute__((ext_vector_type(4))) float f32x4;  // MFMA C/D frag

__device__ inline unsigned short f2bf(float f) {
    __hip_bfloat16 h = __float2bfloat16(f);
    return *reinterpret_cast<unsigned short*>(&h);
}

// ---------------------------------------------------------------------------
// prep: fp32 -> bf16 rows; X rows: sq1[r] = ||x||^2 * C_EXP; X_train rows:
// sqal[r] = {||t||^2 * C_EXP, alpha[r]} (packed: gemm loop has no loose
// global loads -> exact vmcnt counting).
// ---------------------------------------------------------------------------
__global__ __launch_bounds__(256) void prep_kernel(
    const float* __restrict__ X, const float* __restrict__ T,
    const float* __restrict__ alpha,
    unsigned short* __restrict__ Xb, unsigned short* __restrict__ Tb,
    float* __restrict__ sq1, float2* __restrict__ sqal)
{
    const int row  = blockIdx.x * 4 + (threadIdx.x >> 6);
    const int lane = threadIdx.x & 63;
    const float* src; unsigned short* dst; int r; bool isX;
    if (row < M_DIM) { src = X; dst = Xb; r = row; isX = true; }
    else             { src = T; dst = Tb; r = row - M_DIM; isX = false; }

    const float4* s4 = reinterpret_cast<const float4*>(src + (size_t)r * D_DIM);
    float4 v = s4[lane];
    float ss = v.x * v.x + v.y * v.y + v.z * v.z + v.w * v.w;

    ushort4 b4;
    b4.x = f2bf(v.x); b4.y = f2bf(v.y); b4.z = f2bf(v.z); b4.w = f2bf(v.w);
    reinterpret_cast<ushort4*>(dst + (size_t)r * D_DIM)[lane] = b4;

    #pragma unroll
    for (int o = 1; o < 64; o <<= 1) ss += __shfl_xor(ss, o);
    if (lane == 0) {
        if (isX) sq1[r] = ss * C_EXP;
        else     sqal[r] = make_float2(ss * C_EXP, alpha[r]);
    }
}

// ---------------------------------------------------------------------------
// Fused RBF GEMM, occupancy-first counted-vmcnt pipeline:
//  - wave = 32 A-rows, full K=256 resident as MFMA frags (af[2][8] = 64
//    VGPR; ~115 total, __launch_bounds__(512,4) caps at 128) -> 4 waves/
//    SIMD, 16 waves/CU: the 2-phase stage/barrier stall of one block hides
//    under the other's MFMA (m114 overlap — R7 had only 2 waves/SIMD).
//  - block = 8 waves = 256 rows x one 256-col slice; grid 512.
//  - B staged cooperatively ONCE per block per 16-col chunk (1
//    global_load_lds per wave) into 8 x 8 KB LDS ring, LOOKAHEAD=4:
//    stage(i+4) -> s_waitcnt vmcnt(4) -> s_barrier -> compute(i).
//    Never drains mid-loop. Writer buf (i+4)&7 vs oldest live reader
//    (i-1)&7 differ 5 mod 8 -> race-free with one barrier per chunk.
//  - LDS slot swizzle s' = s ^ (col&7) on both sides (G21): conflict-free.
// MFMA frag layouts (m89/m91): A/B lane l: row/col=l&15, k=(l>>4)*8..+7
// per 32-k window; C/D: col=lane&15, row=(lane>>4)*4+reg.
// blockIdx&31 = cslice -> XCD-pinned B slices, all staging L2-resident.
// ---------------------------------------------------------------------------
__global__ __launch_bounds__(512, 4) void gemm_kernel(
    const unsigned short* __restrict__ Xb, const unsigned short* __restrict__ Tb,
    const float* __restrict__ sq1, const float2* __restrict__ sqal,
    float* __restrict__ part)
{
    __shared__ __align__(16) char smem[LDS_BYTES];
    const int cslice = blockIdx.x & 31;
    const int quad   = blockIdx.x >> 5;
    const int wid    = threadIdx.x >> 6;          // wave 0..7
    const int lane   = threadIdx.x & 63;
    const int l15    = lane & 15;
    const int lg     = lane >> 4;

    const int rowbase = quad * 256 + wid * 32;    // this wave's 32 rows
    const int colbase = cslice * 256;

    // ---- A fragments: 32 rows x full K in registers (16 x dwordx4) ----
    short8 af[2][8];
    #pragma unroll
    for (int m = 0; m < 2; ++m)
        #pragma unroll
        for (int ks = 0; ks < 8; ++ks)
            af[m][ks] = *(const short8*)(Xb +
                (size_t)(rowbase + m * 16 + l15) * D_DIM + ks * 32 + lg * 8);

    float4 s1v[2];
    #pragma unroll
    for (int m = 0; m < 2; ++m)
        s1v[m] = *reinterpret_cast<const float4*>(sq1 + rowbase + m * 16 + lg * 4);
    float s1max = -1e30f;
    #pragma unroll
    for (int m = 0; m < 2; ++m)
        #pragma unroll
        for (int r = 0; r < 4; ++r) s1max = fmaxf(s1max, s1v[m][r]);

    // Pin plain global loads older than the staging stream (exact counting).
    asm volatile("s_waitcnt vmcnt(0)" ::: "memory");

    const char* TbB = (const char*)Tb;
    const char* SaB = (const char*)sqal + (size_t)colbase * 8;

    // sqal slice (2 KB): every wave issues the same 2 ops (identical bytes
    // to identical LDS addresses -> benign; keeps vmcnt counts uniform).
    #pragma unroll
    for (int s = 0; s < 2; ++s)
        __builtin_amdgcn_global_load_lds(
            (const __attribute__((address_space(1))) void*)(SaB + s * 1024 + lane * 16),
            (__attribute__((address_space(3))) void*)(smem + SQAL_OFF + s * 1024), 16, 0, 0);

    // stage chunk i into ring buffer i&7: ONE op per wave (8 KB/block total)
    auto stage = [&](int i) {
        char* buf = smem + (i & 7) * BUFB;
        const int col_local = wid * 2 + (lane >> 5);  // 2 cols per 1 KB unit
        const size_t src = (size_t)(colbase + i * 16 + col_local) * 512
                         + (size_t)(((lane & 31) ^ (col_local & 7)) * 16);
        __builtin_amdgcn_global_load_lds(
            (const __attribute__((address_space(1))) void*)(TbB + src),
            (__attribute__((address_space(3))) void*)(buf + wid * 1024), 16, 0, 0);
    };

    float psum[2][4];
    #pragma unroll
    for (int m = 0; m < 2; ++m)
        #pragma unroll
        for (int r = 0; r < 4; ++r) psum[m][r] = 0.0f;

    auto compute = [&](int i) {
        const char* buf = smem + (i & 7) * BUFB;
        f32x4 acc[2];
        acc[0] = (f32x4)0.0f; acc[1] = (f32x4)0.0f;
        #pragma unroll
        for (int ks = 0; ks < 8; ++ks) {
            const short8 bf = *(const short8*)(buf + l15 * 512 +
                (((ks * 4 + lg) ^ (l15 & 7)) * 16));
            acc[0] = __builtin_amdgcn_mfma_f32_16x16x32_bf16(af[0][ks], bf, acc[0], 0, 0, 0);
            acc[1] = __builtin_amdgcn_mfma_f32_16x16x32_bf16(af[1][ks], bf, acc[1], 0, 0, 0);
        }
        const float2 sa = *(const float2*)(smem + SQAL_OFF + (i * 16 + l15) * 8);
        float amax = acc[0][0];
        #pragma unroll
        for (int m = 0; m < 2; ++m)
            #pragma unroll
            for (int r = 0; r < 4; ++r) amax = fmaxf(amax, acc[m][r]);
        const float bound = fmaf(amax, K_ACC, s1max + sa.x); // >= every arg
        if (!__all(bound < SKIP_THR)) {
            #pragma unroll
            for (int m = 0; m < 2; ++m)
                #pragma unroll
                for (int r = 0; r < 4; ++r) {
                    const float arg = fmaf(acc[m][r], K_ACC, s1v[m][r] + sa.x);
                    psum[m][r] = fmaf(__builtin_amdgcn_exp2f(arg), sa.y, psum[m][r]);
                }
        }
    };

    #pragma unroll
    for (int i = 0; i < LOOKAHEAD; ++i) stage(i);
    #pragma unroll
    for (int i = 0; i < NCHUNK; ++i) {
        if (i + LOOKAHEAD < NCHUNK) {
            stage(i + LOOKAHEAD);                        // 1 op, buf (i+4)&7
            asm volatile("s_waitcnt vmcnt(4)" ::: "memory"); // chunk i landed
        } else if (i + 3 < NCHUNK) {
            asm volatile("s_waitcnt vmcnt(3)" ::: "memory");
        } else if (i + 2 < NCHUNK) {
            asm volatile("s_waitcnt vmcnt(2)" ::: "memory");
        } else if (i + 1 < NCHUNK) {
            asm volatile("s_waitcnt vmcnt(1)" ::: "memory");
        } else {
            asm volatile("s_waitcnt vmcnt(0)" ::: "memory");
        }
        __builtin_amdgcn_s_barrier();   // all waves' chunk-i writes visible
        compute(i);
    }

    // ---- reduce over the 16 l15-lanes (cols) and store partials ----
    #pragma unroll
    for (int m = 0; m < 2; ++m) {
        float4 pv;
        #pragma unroll
        for (int r = 0; r < 4; ++r) {
            float p = psum[m][r];
            p += __shfl_xor(p, 1);
            p += __shfl_xor(p, 2);
            p += __shfl_xor(p, 4);
            p += __shfl_xor(p, 8);
            ((float*)&pv)[r] = p;
        }
        if (l15 == 0) // 4 lanes (lg=0..3) write 4 consecutive floats each
            *reinterpret_cast<float4*>(part + (size_t)cslice * M_DIM +
                                       rowbase + m * 16 + lg * 4) = pv;
    }
}

// ---------------------------------------------------------------------------
// reduce: out[i] = sum over 32 col-slices of part[cs][i]. 16 blocks x 256.
// ---------------------------------------------------------------------------
__global__ __launch_bounds__(256) void reduce_kernel(
    const float* __restrict__ part, float* __restrict__ out)
{
    const int gi = blockIdx.x * 256 + threadIdx.x;
    float s = 0.0f;
    #pragma unroll
    for (int b = 0; b < NSLICE; ++b) s += part[(size_t)b * M_DIM + gi];
    out[gi] = s;
}

extern "C" void kernel_launch(void* const* d_in, const int* in_sizes, int n_in,
                              void* d_out, int out_size, void* d_ws, size_t ws_size,
                              hipStream_t stream)
{
    const float* X  = (const float*)d_in[0];
    const float* T  = (const float*)d_in[1];
    const float* al = (const float*)d_in[2];
    float* out = (float*)d_out;

    char* ws = (char*)d_ws;
    unsigned short* Xb = (unsigned short*)ws;                               // 2 MiB
    unsigned short* Tb = (unsigned short*)(ws + (size_t)M_DIM * D_DIM * 2); // 4 MiB
    float* sq1  = (float*)(ws + (size_t)(M_DIM + N_DIM) * D_DIM * 2);       // 16 KiB
    float2* sqal = (float2*)(sq1 + M_DIM);                                  // 64 KiB
    float* part = (float*)(sqal + N_DIM);                                   // 512 KiB

    prep_kernel<<<(M_DIM + N_DIM) / 4, 256, 0, stream>>>(X, T, al, Xb, Tb, sq1, sqal);
    gemm_kernel<<<16 * NSLICE, 512, 0, stream>>>(Xb, Tb, sq1, sqal, part);
    reduce_kernel<<<M_DIM / 256, 256, 0, stream>>>(part, out);
}